// Round 11
// baseline (962.272 us; speedup 1.0000x reference)
//
#include <hip/hip_runtime.h>
#include <hip/hip_bf16.h>

// GCN 2-layer + global_add_pool on MI355X.
// R10 changes:
//  - agg2+pool FLIPPED (gather -> stream+scatter): P[g] = sum over edges
//    (s,d) of dn[d]*T[s]. Edges binned by SRC bucket (256 nodes); one block
//    per bucket stages T-slice (32KB) + 128-graph accumulator (32KB) in LDS;
//    per edge per lane = 1 LDS read + 1 LDS atomicAdd. T is read as a
//    coalesced 12.8MB stream instead of a 205MB random gather (R10 counters:
//    agg2 57us pinned at ~3.2M L2 line-misses regardless of unroll/VALU ->
//    per-CU outstanding-miss cap; the only win is deleting the gather).
//    Two feature-half passes (64KB LDS each); self-loops in-bucket; flush
//    via global atomicAdd into P.
//  - agg1 unchanged (per-node output + ReLU: not poolable; gather stays).

typedef _Float16 f16x8 __attribute__((ext_vector_type(8)));
typedef float f32x4 __attribute__((ext_vector_type(4)));

#define BCHUNK 4096

static __device__ __forceinline__ float f16lo(unsigned int u) {
    union { unsigned short s; _Float16 h; } c; c.s = (unsigned short)(u & 0xffff);
    return (float)c.h;
}
static __device__ __forceinline__ float f16hi(unsigned int u) {
    union { unsigned short s; _Float16 h; } c; c.s = (unsigned short)(u >> 16);
    return (float)c.h;
}
static __device__ __forceinline__ float f16u(unsigned short s) {
    union { unsigned short s; _Float16 h; } c; c.s = s;
    return (float)c.h;
}
static __device__ __forceinline__ unsigned int pack2f16(float x, float y) {
    union { unsigned short s; _Float16 h; } a, b;
    a.h = (_Float16)x; b.h = (_Float16)y;
    return (unsigned int)a.s | ((unsigned int)b.s << 16);
}

// ---------------- bucket binning (dst, for agg1 CSR) ----------------

__global__ __launch_bounds__(256) void bin_hist(const int* __restrict__ ei,
                                                int* __restrict__ counts,
                                                int E, int NB, int NBLK, int SRC) {
    __shared__ int hist[256];
    int t = threadIdx.x, blk = blockIdx.x;
    for (int b = t; b < NB; b += 256) hist[b] = 0;
    __syncthreads();
    int base = blk * BCHUNK;
    int end = min(E, base + BCHUNK);
    const int* key = SRC ? ei : (ei + E);
    for (int e = base + t; e < end; e += 256)
        atomicAdd(&hist[key[e] >> 8], 1);
    __syncthreads();
    for (int b = t; b < NB; b += 256) counts[b * NBLK + blk] = hist[b];
}

__global__ __launch_bounds__(256) void bin_scatter(const int* __restrict__ ei,
                                                   const int* __restrict__ counts,
                                                   unsigned int* __restrict__ bedges,
                                                   int E, int NB, int NBLK) {
    __shared__ int lcur[256];
    int t = threadIdx.x, blk = blockIdx.x;
    for (int b = t; b < NB; b += 256) lcur[b] = counts[b * NBLK + blk];
    __syncthreads();
    int base = blk * BCHUNK;
    int end = min(E, base + BCHUNK);
    for (int e = base + t; e < end; e += 256) {
        int s = ei[e];
        int d = ei[E + e];
        int pos = atomicAdd(&lcur[d >> 8], 1);
        bedges[pos] = (unsigned int)s | ((unsigned int)(d & 255) << 16);
    }
}

// src-binned scatter: payload = (slocal | g<<8, dinv[d])
__global__ __launch_bounds__(256) void bin_scatter2(const int* __restrict__ ei,
                                                    const int* __restrict__ counts2,
                                                    const int* __restrict__ batch,
                                                    const float* __restrict__ dinv,
                                                    uint2* __restrict__ bedges2,
                                                    int E, int NB2, int NBLK) {
    __shared__ int lcur[256];
    int t = threadIdx.x, blk = blockIdx.x;
    for (int b = t; b < NB2; b += 256) lcur[b] = counts2[b * NBLK + blk];
    __syncthreads();
    int base = blk * BCHUNK;
    int end = min(E, base + BCHUNK);
    for (int e = base + t; e < end; e += 256) {
        int s = ei[e];
        int d = ei[E + e];
        int pos = atomicAdd(&lcur[s >> 8], 1);
        bedges2[pos] = make_uint2((unsigned int)(s & 255) | ((unsigned int)batch[d] << 8),
                                  __float_as_uint(dinv[d]));
    }
}

// per-bucket degree count via LDS histogram (coalesced cnt write)
__global__ __launch_bounds__(256) void deg_buckets(const unsigned int* __restrict__ bedges,
                                                   const int* __restrict__ counts,
                                                   int* __restrict__ cnt,
                                                   int E, int N, int NB, int NBLK) {
    __shared__ int lcnt[256];
    int b = blockIdx.x, t = threadIdx.x;
    lcnt[t] = 0;
    __syncthreads();
    int bstart = counts[b * NBLK];
    int bend = (b + 1 < NB) ? counts[(b + 1) * NBLK] : E;
    for (int i = bstart + t; i < bend; i += 256)
        atomicAdd(&lcnt[bedges[i] >> 16], 1);
    __syncthreads();
    int node = (b << 8) + t;
    if (node < N) cnt[node] = lcnt[t];
}

// one block per bucket: CSR fill into the bucket's own (L2-local) window
__global__ __launch_bounds__(256) void fill_buckets(const unsigned int* __restrict__ bedges,
                                                    const int* __restrict__ counts,
                                                    const int* __restrict__ row_start,
                                                    int* __restrict__ srcs,
                                                    int E, int N, int NB, int NBLK) {
    __shared__ int lcur[256];
    int b = blockIdx.x, t = threadIdx.x;
    int node = (b << 8) + t;
    lcur[t] = (node < N) ? row_start[node] : 0;
    __syncthreads();
    int bstart = counts[b * NBLK];
    int bend = (b + 1 < NB) ? counts[(b + 1) * NBLK] : E;
    for (int i = bstart + t; i < bend; i += 256) {
        unsigned int p = bedges[i];
        int pos = atomicAdd(&lcur[p >> 16], 1);
        srcs[pos] = (int)(p & 0xffffu);
    }
}

// ---------------- scans ----------------

__global__ void block_sums(const int* __restrict__ data, int* __restrict__ bsum, int n) {
    __shared__ int s[256];
    int base = blockIdx.x * 1024;
    int t = threadIdx.x;
    int v = 0;
#pragma unroll
    for (int i = 0; i < 4; i++) {
        int idx = base + t * 4 + i;
        if (idx < n) v += data[idx];
    }
    s[t] = v;
    __syncthreads();
    for (int off = 128; off > 0; off >>= 1) {
        if (t < off) s[t] += s[t + off];
        __syncthreads();
    }
    if (t == 0) bsum[blockIdx.x] = s[0];
}

__global__ void scan_bsum(int* __restrict__ bsum, int nb) {
    int lane = threadIdx.x & 63;
    int v = (lane < nb) ? bsum[lane] : 0;
    int incl = v;
#pragma unroll
    for (int off = 1; off < 64; off *= 2) {
        int u = __shfl_up(incl, off);
        if (lane >= off) incl += u;
    }
    if (lane < nb) bsum[lane] = incl - v;  // exclusive
}

__global__ void scan_apply(int* __restrict__ data, const int* __restrict__ bsum, int n) {
    __shared__ int s[256];
    int base = blockIdx.x * 1024;
    int t = threadIdx.x;
    int loc[4];
    int v = 0;
#pragma unroll
    for (int i = 0; i < 4; i++) {
        int idx = base + t * 4 + i;
        loc[i] = (idx < n) ? data[idx] : 0;
        v += loc[i];
    }
    s[t] = v;
    __syncthreads();
    for (int off = 1; off < 256; off *= 2) {
        int u = (t >= off) ? s[t - off] : 0;
        __syncthreads();
        s[t] += u;
        __syncthreads();
    }
    int excl = s[t] - v + bsum[blockIdx.x];
#pragma unroll
    for (int i = 0; i < 4; i++) {
        int idx = base + t * 4 + i;
        if (idx < n) { data[idx] = excl; excl += loc[i]; }
    }
}

__global__ void scan_nodes(const int* __restrict__ cnt, const int* __restrict__ bsum,
                           int* __restrict__ row_start, float* __restrict__ dinv, int n) {
    __shared__ int s[256];
    int base = blockIdx.x * 1024;
    int t = threadIdx.x;
    int loc[4];
    int v = 0;
#pragma unroll
    for (int i = 0; i < 4; i++) {
        int idx = base + t * 4 + i;
        loc[i] = (idx < n) ? cnt[idx] : 0;
        v += loc[i];
    }
    s[t] = v;
    __syncthreads();
    for (int off = 1; off < 256; off *= 2) {
        int u = (t >= off) ? s[t - off] : 0;
        __syncthreads();
        s[t] += u;
        __syncthreads();
    }
    int excl = s[t] - v + bsum[blockIdx.x];
#pragma unroll
    for (int i = 0; i < 4; i++) {
        int idx = base + t * 4 + i;
        if (idx < n) {
            row_start[idx] = excl;
            dinv[idx] = rsqrtf((float)loc[i] + 1.0f);
            excl += loc[i];
        }
    }
}

// ---------------- W fragment prep ----------------
__global__ void wprep(const float* __restrict__ W, _Float16* __restrict__ wfrag) {
    int idx = blockIdx.x * 256 + threadIdx.x;  // 2048 total
    if (idx >= 2048) return;
    int lane = idx & 63;
    int kc = (idx >> 6) & 3;
    int nb = idx >> 8;
    int col = nb * 16 + (lane & 15);
    int krow = kc * 32 + (lane >> 4) * 8;
#pragma unroll
    for (int j = 0; j < 8; j++)
        wfrag[idx * 8 + j] = (_Float16)W[(krow + j) * 128 + col];
}

// ---------------- GEMM: C[row][128] = dinv[row] * (A@W)[row], fp16 MFMA ----------------
__global__ __launch_bounds__(256) void gemm_mfma_f32in(const float* __restrict__ A,
                                                       const _Float16* __restrict__ wfrag,
                                                       const float* __restrict__ dinv,
                                                       _Float16* __restrict__ C, int M) {
    __shared__ _Float16 As[128 * 136];
    int t = threadIdx.x;
    int row0 = blockIdx.x * 128;

    const float4* A4 = (const float4*)A;
#pragma unroll
    for (int it = 0; it < 16; it++) {
        int v = it * 256 + t;
        int row = v >> 5;
        int seg = v & 31;
        float4 val = make_float4(0.f, 0.f, 0.f, 0.f);
        if (row0 + row < M) val = A4[(size_t)(row0 + row) * 32 + seg];
        _Float16* p = &As[row * 136 + seg * 4];
        p[0] = (_Float16)val.x; p[1] = (_Float16)val.y;
        p[2] = (_Float16)val.z; p[3] = (_Float16)val.w;
    }
    __syncthreads();

    int wv = t >> 6;
    int lane = t & 63;
    int lrow = lane & 15;
    int lq = lane >> 4;

    f32x4 acc[2][8];
#pragma unroll
    for (int i = 0; i < 2; i++)
#pragma unroll
        for (int j = 0; j < 8; j++) acc[i][j] = (f32x4){0.f, 0.f, 0.f, 0.f};

#pragma unroll
    for (int kc = 0; kc < 4; kc++) {
        int k0 = kc * 32;
        f16x8 a0 = *((const f16x8*)&As[(wv * 32 + lrow) * 136 + k0 + lq * 8]);
        f16x8 a1 = *((const f16x8*)&As[(wv * 32 + 16 + lrow) * 136 + k0 + lq * 8]);
#pragma unroll
        for (int nb = 0; nb < 8; nb++) {
            f16x8 b = ((const f16x8*)wfrag)[(nb * 4 + kc) * 64 + lane];
            acc[0][nb] = __builtin_amdgcn_mfma_f32_16x16x32_f16(a0, b, acc[0][nb], 0, 0, 0);
            acc[1][nb] = __builtin_amdgcn_mfma_f32_16x16x32_f16(a1, b, acc[1][nb], 0, 0, 0);
        }
    }

    // C/D layout: col = lane&15, row = (lane>>4)*4 + reg. Prescaled store.
#pragma unroll
    for (int ti = 0; ti < 2; ti++) {
#pragma unroll
        for (int r = 0; r < 4; r++) {
            int row = row0 + wv * 32 + ti * 16 + lq * 4 + r;
            if (row < M) {
                float sc = dinv[row];
#pragma unroll
                for (int nb = 0; nb < 8; nb++)
                    C[(size_t)row * 128 + nb * 16 + lrow] = (_Float16)(acc[ti][nb][r] * sc);
            }
        }
    }
}

// ---------------- agg1: one wave per node, prescaled fp16 table, unroll x16 ----------------
// ob[node] = dn * relu(dn*sum + b1), prescaled by dinv for the next stage.
__global__ __launch_bounds__(256) void agg1(const _Float16* __restrict__ tab,
                                            const int* __restrict__ srcs,
                                            const int* __restrict__ row_start,
                                            const int* __restrict__ cnt,
                                            const float* __restrict__ dinv,
                                            const float* __restrict__ bias,
                                            _Float16* __restrict__ obout, int n) {
    int node = blockIdx.x * 4 + (threadIdx.x >> 6);
    if (node >= n) return;
    int lane = threadIdx.x & 63;
    int s0 = row_start[node];
    int c = cnt[node];
    float dn = dinv[node];
    const unsigned int* T = (const unsigned int*)tab;
    float ax = 0.f, ay = 0.f, bx = 0.f, by = 0.f;
    int e = 0;
    for (; e + 16 <= c; e += 16) {
        int si[16];
#pragma unroll
        for (int i = 0; i < 16; i++) si[i] = srcs[s0 + e + i];
        unsigned int v[16];
#pragma unroll
        for (int i = 0; i < 16; i++) v[i] = T[(size_t)si[i] * 64 + lane];
#pragma unroll
        for (int i = 0; i < 16; i++) {
            if (i & 1) { bx += f16lo(v[i]); by += f16hi(v[i]); }
            else       { ax += f16lo(v[i]); ay += f16hi(v[i]); }
        }
    }
    for (; e + 4 <= c; e += 4) {
        int si[4];
#pragma unroll
        for (int i = 0; i < 4; i++) si[i] = srcs[s0 + e + i];
        unsigned int v[4];
#pragma unroll
        for (int i = 0; i < 4; i++) v[i] = T[(size_t)si[i] * 64 + lane];
#pragma unroll
        for (int i = 0; i < 4; i++) {
            if (i & 1) { bx += f16lo(v[i]); by += f16hi(v[i]); }
            else       { ax += f16lo(v[i]); ay += f16hi(v[i]); }
        }
    }
    for (; e < c; e++) {
        unsigned int v = T[(size_t)srcs[s0 + e] * 64 + lane];
        ax += f16lo(v); ay += f16hi(v);
    }
    unsigned int hv = T[(size_t)node * 64 + lane];
    ax += f16lo(hv); ay += f16hi(hv);
    ax += bx; ay += by;
    float2 bv = ((const float2*)bias)[lane];
    float ox = dn * fmaxf(fmaf(dn, ax, bv.x), 0.f);
    float oy = dn * fmaxf(fmaf(dn, ay, bv.y), 0.f);
    ((unsigned int*)obout)[(size_t)node * 64 + lane] = pack2f16(ox, oy);
}

// ---------------- flipped agg2 + pool ----------------
// One block per src bucket (256 nodes). LDS: T-slice half (256 x 64 f16 =
// 32KB) + accumulator (128 g x 64 f = 32KB). Per edge per lane: 1 LDS read
// + 1 LDS atomicAdd. Self-loops handled in-bucket. HALF selects features
// [HALF*64, HALF*64+64).
template <int HALF>
__global__ __launch_bounds__(1024) void agg2_flip(const _Float16* __restrict__ tab,
                                                  const uint2* __restrict__ bedges2,
                                                  const int* __restrict__ counts2,
                                                  const int* __restrict__ batch,
                                                  const float* __restrict__ dinv,
                                                  float* __restrict__ P,
                                                  int E, int N, int NB2, int NBLK) {
    __shared__ unsigned short Tl[256 * 64];  // 32 KB
    __shared__ float Pl[128 * 64];           // 32 KB
    int b = blockIdx.x, tid = threadIdx.x;
    for (int i = tid; i < 128 * 64; i += 1024) Pl[i] = 0.f;
    const unsigned short* Tg = (const unsigned short*)tab;
    int nbase = b << 8;
    int nodes = min(256, N - nbase);
    for (int i = tid; i < nodes * 64; i += 1024) {
        int row = i >> 6, f = i & 63;
        Tl[(row << 6) + f] = Tg[(size_t)(nbase + row) * 128 + HALF * 64 + f];
    }
    __syncthreads();
    int w = tid >> 6, lane = tid & 63;
    int bstart = counts2[b * NBLK];
    int bend = (b + 1 < NB2) ? counts2[(b + 1) * NBLK] : E;
    // edges: 16 waves, 4 contiguous edges per wave step (4 indep chains)
    for (int i = bstart + w * 4; i < bend; i += 64) {
        uint2 p0, p1, p2, p3;
        int m = bend - i;
        p0 = bedges2[i];
        if (m > 1) p1 = bedges2[i + 1];
        if (m > 2) p2 = bedges2[i + 2];
        if (m > 3) p3 = bedges2[i + 3];
        float v0 = f16u(Tl[((p0.x & 255) << 6) + lane]);
        atomicAdd(&Pl[((p0.x >> 8) << 6) + lane], __uint_as_float(p0.y) * v0);
        if (m > 1) {
            float v1 = f16u(Tl[((p1.x & 255) << 6) + lane]);
            atomicAdd(&Pl[((p1.x >> 8) << 6) + lane], __uint_as_float(p1.y) * v1);
        }
        if (m > 2) {
            float v2 = f16u(Tl[((p2.x & 255) << 6) + lane]);
            atomicAdd(&Pl[((p2.x >> 8) << 6) + lane], __uint_as_float(p2.y) * v2);
        }
        if (m > 3) {
            float v3 = f16u(Tl[((p3.x & 255) << 6) + lane]);
            atomicAdd(&Pl[((p3.x >> 8) << 6) + lane], __uint_as_float(p3.y) * v3);
        }
    }
    // self-loops: P[batch[d]] += dinv[d] * T[d] for d in bucket
    for (int i = w; i < nodes; i += 16) {
        int node = nbase + i;
        float dn = dinv[node];
        int g = batch[node];
        float v = f16u(Tl[(i << 6) + lane]);
        atomicAdd(&Pl[(g << 6) + lane], dn * v);
    }
    __syncthreads();
    for (int i = tid; i < 128 * 64; i += 1024) {
        float v = Pl[i];
        if (v != 0.f) {
            int g = i >> 6, f = i & 63;
            atomicAdd(&P[g * 128 + HALF * 64 + f], v);
        }
    }
}

// ---------------- out = P @ W2 + n_g * b2, one block per graph ----------------
__global__ __launch_bounds__(128) void gemm_small(const float* __restrict__ P,
                                                  const float* __restrict__ W2,
                                                  const float* __restrict__ b2,
                                                  const int* __restrict__ batch,
                                                  float* __restrict__ out, int n) {
    __shared__ float prow[128];
    int g = blockIdx.x;
    int c = threadIdx.x;
    prow[c] = P[g * 128 + c];
    __syncthreads();
    int lo = 0, hi = n;
    while (lo < hi) { int mid = (lo + hi) >> 1; if (batch[mid] < g) lo = mid + 1; else hi = mid; }
    int start = lo;
    hi = n;
    while (lo < hi) { int mid = (lo + hi) >> 1; if (batch[mid] < g + 1) lo = mid + 1; else hi = mid; }
    float ng = (float)(lo - start);
    float acc = 0.f;
#pragma unroll 8
    for (int k = 0; k < 128; k++) acc = fmaf(prow[k], W2[k * 128 + c], acc);
    out[g * 128 + c] = acc + ng * b2[c];
}

extern "C" void kernel_launch(void* const* d_in, const int* in_sizes, int n_in,
                              void* d_out, int out_size, void* d_ws, size_t ws_size,
                              hipStream_t stream) {
    const float* x  = (const float*)d_in[0];
    const int*   ei = (const int*)d_in[1];
    const int*   batch = (const int*)d_in[2];
    const float* W1 = (const float*)d_in[3];
    const float* b1 = (const float*)d_in[4];
    const float* W2 = (const float*)d_in[5];
    const float* b2 = (const float*)d_in[6];
    float* out = (float*)d_out;

    const int N = in_sizes[2];       // 50000 (assumed <= 65536)
    const int E = in_sizes[1] / 2;   // 800000

    const int NB = (N + 255) >> 8;              // 196 buckets (dst and src)
    const int NBLK = (E + BCHUNK - 1) / BCHUNK; // 196 chunks
    const int ncounts = NB * NBLK;              // 38416

    // workspace layout
    _Float16* hb = (_Float16*)d_ws;                  // N*128 halves
    _Float16* ob = hb + (size_t)N * 128;             // N*128 halves
    int* cnt  = (int*)(ob + (size_t)N * 128);        // N
    int* row_start = cnt + N;                        // N
    float* dinv    = (float*)(row_start + N);        // N
    int* srcs      = (int*)(dinv + N);               // E
    unsigned int* bedges = (unsigned int*)(srcs + E);// E
    uint2* bedges2 = (uint2*)(bedges + E);           // E uint2
    int* counts    = (int*)(bedges2 + E);            // NB*NBLK
    int* counts2   = counts + ncounts;               // NB*NBLK
    _Float16* wfrag1 = (_Float16*)(counts2 + ncounts);// 128*128
    float* P       = (float*)(wfrag1 + 128 * 128);   // 128*128 f32
    int* bsum      = (int*)(P + 128 * 128);          // <=64
    int* bsum2     = bsum + 64;                      // <=64

    const int nbc = (ncounts + 1023) / 1024;  // <=64
    const int nbn = (N + 1023) / 1024;        // <=64

    hipMemsetAsync(P, 0, 128 * 128 * sizeof(float), stream);
    wprep<<<8, 256, 0, stream>>>(W1, wfrag1);

    // --- dst binning + CSR build (for agg1) ---
    bin_hist<<<NBLK, 256, 0, stream>>>(ei, counts, E, NB, NBLK, 0);
    block_sums<<<nbc, 256, 0, stream>>>(counts, bsum, ncounts);
    scan_bsum<<<1, 64, 0, stream>>>(bsum, nbc);
    scan_apply<<<nbc, 256, 0, stream>>>(counts, bsum, ncounts);
    bin_scatter<<<NBLK, 256, 0, stream>>>(ei, counts, bedges, E, NB, NBLK);
    deg_buckets<<<NB, 256, 0, stream>>>(bedges, counts, cnt, E, N, NB, NBLK);
    block_sums<<<nbn, 256, 0, stream>>>(cnt, bsum, N);
    scan_bsum<<<1, 64, 0, stream>>>(bsum, nbn);
    scan_nodes<<<nbn, 256, 0, stream>>>(cnt, bsum, row_start, dinv, N);
    fill_buckets<<<NB, 256, 0, stream>>>(bedges, counts, row_start, srcs, E, N, NB, NBLK);

    // --- src binning (for flipped agg2) ---
    bin_hist<<<NBLK, 256, 0, stream>>>(ei, counts2, E, NB, NBLK, 1);
    block_sums<<<nbc, 256, 0, stream>>>(counts2, bsum2, ncounts);
    scan_bsum<<<1, 64, 0, stream>>>(bsum2, nbc);
    scan_apply<<<nbc, 256, 0, stream>>>(counts2, bsum2, ncounts);
    bin_scatter2<<<NBLK, 256, 0, stream>>>(ei, counts2, batch, dinv, bedges2, E, NB, NBLK);

    const int gemm_grid = (N + 127) / 128;
    const int agg_grid = (N + 3) / 4;

    // layer 1: hb = dinv*(x@W1) ; ob = dinv*relu(dn*sum + b1)
    gemm_mfma_f32in<<<gemm_grid, 256, 0, stream>>>(x, wfrag1, dinv, hb, N);
    agg1<<<agg_grid, 256, 0, stream>>>(hb, srcs, row_start, cnt, dinv, b1, ob, N);
    // layer 2 (flipped): P = pool(Â o) via stream+scatter ; out = P@W2 + n_g*b2
    agg2_flip<0><<<NB, 1024, 0, stream>>>(ob, bedges2, counts2, batch, dinv, P, E, N, NB, NBLK);
    agg2_flip<1><<<NB, 1024, 0, stream>>>(ob, bedges2, counts2, batch, dinv, P, E, N, NB, NBLK);
    gemm_small<<<128, 128, 0, stream>>>(P, W2, b2, batch, out, N);
}

// Round 12
// 361.334 us; speedup vs baseline: 2.6631x; 2.6631x over previous
//
#include <hip/hip_runtime.h>
#include <hip/hip_bf16.h>

// GCN 2-layer + global_add_pool on MI355X.
// R11 changes: REVERT R11's LDS-atomic flip (382us/dispatch: HIP lowers LDS
// f32 atomicAdd to a CAS loop -> serialization; VALU 3%, hbm 0.4%). Back to
// the R10 gather structure (best: 238us), plus:
//  - 4-edge-wide gather: lane = slot(4) x feature-quad(16); one uint4 load
//    per lane = 4 edges x 256B = 1KB/instruction (vs R10's 1 edge/instr,
//    4B/lane). Unroll 4 -> 16 edges in flight with 1/4 the load instrs.
//    Slot-reduce = 2 shuffles x 8 accumulators.
//  - Kernel count 18 -> 9: fill_buckets computes bucket histogram + scan
//    internally and writes row_start/dinv directly (deletes deg_buckets,
//    scan_nodes, cnt + its scan chain); counts scanned by one single-block
//    kernel; wprep + P-zero fused into setup; cnt loads replaced by
//    row_start[node+1] sentinel.

typedef _Float16 f16x8 __attribute__((ext_vector_type(8)));
typedef float f32x4 __attribute__((ext_vector_type(4)));

#define BCHUNK 4096

static __device__ __forceinline__ float f16lo(unsigned int u) {
    union { unsigned short s; _Float16 h; } c; c.s = (unsigned short)(u & 0xffff);
    return (float)c.h;
}
static __device__ __forceinline__ float f16hi(unsigned int u) {
    union { unsigned short s; _Float16 h; } c; c.s = (unsigned short)(u >> 16);
    return (float)c.h;
}
static __device__ __forceinline__ unsigned int pack2f16(float x, float y) {
    union { unsigned short s; _Float16 h; } a, b;
    a.h = (_Float16)x; b.h = (_Float16)y;
    return (unsigned int)a.s | ((unsigned int)b.s << 16);
}

// ---------------- setup: wprep(W1) + zero P ----------------
__global__ __launch_bounds__(256) void setup(const float* __restrict__ W1,
                                             _Float16* __restrict__ wfrag,
                                             float* __restrict__ P) {
    int idx = blockIdx.x * 256 + threadIdx.x;
    if (idx < 2048) {
        int lane = idx & 63;
        int kc = (idx >> 6) & 3;
        int nb = idx >> 8;
        int col = nb * 16 + (lane & 15);
        int krow = kc * 32 + (lane >> 4) * 8;
#pragma unroll
        for (int j = 0; j < 8; j++)
            wfrag[idx * 8 + j] = (_Float16)W1[(krow + j) * 128 + col];
    } else {
        int i = idx - 2048;
        if (i < 128 * 128) P[i] = 0.f;
    }
}

// ---------------- dst-bucket binning ----------------

__global__ __launch_bounds__(256) void bin_hist(const int* __restrict__ ei,
                                                int* __restrict__ counts,
                                                int E, int NB, int NBLK) {
    __shared__ int hist[256];
    int t = threadIdx.x, blk = blockIdx.x;
    for (int b = t; b < NB; b += 256) hist[b] = 0;
    __syncthreads();
    int base = blk * BCHUNK;
    int end = min(E, base + BCHUNK);
    for (int e = base + t; e < end; e += 256)
        atomicAdd(&hist[ei[E + e] >> 8], 1);
    __syncthreads();
    for (int b = t; b < NB; b += 256) counts[b * NBLK + blk] = hist[b];
}

// single-block in-place exclusive scan over n (<= 1024*64) ints
__global__ __launch_bounds__(1024) void scan_counts(int* __restrict__ data, int n) {
    __shared__ int part[1024];
    int t = threadIdx.x;
    int per = (n + 1023) >> 10;
    int base = t * per;
    int sum = 0;
    for (int i = 0; i < per; i++) {
        int idx = base + i;
        if (idx < n) sum += data[idx];
    }
    part[t] = sum;
    __syncthreads();
    for (int off = 1; off < 1024; off *= 2) {
        int u = (t >= off) ? part[t - off] : 0;
        __syncthreads();
        part[t] += u;
        __syncthreads();
    }
    int excl = part[t] - sum;
    for (int i = 0; i < per; i++) {
        int idx = base + i;
        if (idx < n) { int v = data[idx]; data[idx] = excl; excl += v; }
    }
}

__global__ __launch_bounds__(256) void bin_scatter(const int* __restrict__ ei,
                                                   const int* __restrict__ counts,
                                                   unsigned int* __restrict__ bedges,
                                                   int E, int NB, int NBLK) {
    __shared__ int lcur[256];
    int t = threadIdx.x, blk = blockIdx.x;
    for (int b = t; b < NB; b += 256) lcur[b] = counts[b * NBLK + blk];
    __syncthreads();
    int base = blk * BCHUNK;
    int end = min(E, base + BCHUNK);
    for (int e = base + t; e < end; e += 256) {
        int s = ei[e];
        int d = ei[E + e];
        int pos = atomicAdd(&lcur[d >> 8], 1);
        bedges[pos] = (unsigned int)s | ((unsigned int)(d & 255) << 16);
    }
}

// one block per bucket: local histogram + scan -> row_start/dinv, then CSR
// fill into the bucket's own (L2-local) window.
__global__ __launch_bounds__(256) void fill_buckets(const unsigned int* __restrict__ bedges,
                                                    const int* __restrict__ counts,
                                                    int* __restrict__ row_start,
                                                    float* __restrict__ dinv,
                                                    int* __restrict__ srcs,
                                                    int E, int N, int NB, int NBLK) {
    __shared__ int lcnt[256];
    __shared__ int lscan[256];
    __shared__ int lcur[256];
    int b = blockIdx.x, t = threadIdx.x;
    lcnt[t] = 0;
    __syncthreads();
    int bstart = counts[b * NBLK];
    int bend = (b + 1 < NB) ? counts[(b + 1) * NBLK] : E;
    for (int i = bstart + t; i < bend; i += 256)
        atomicAdd(&lcnt[bedges[i] >> 16], 1);
    __syncthreads();
    int v = lcnt[t];
    lscan[t] = v;
    __syncthreads();
    for (int off = 1; off < 256; off *= 2) {
        int u = (t >= off) ? lscan[t - off] : 0;
        __syncthreads();
        lscan[t] += u;
        __syncthreads();
    }
    int excl = lscan[t] - v;
    int node = (b << 8) + t;
    if (node < N) {
        row_start[node] = bstart + excl;
        dinv[node] = rsqrtf((float)v + 1.0f);
        if (node == N - 1) row_start[N] = E;
    }
    lcur[t] = bstart + excl;
    __syncthreads();
    for (int i = bstart + t; i < bend; i += 256) {
        unsigned int p = bedges[i];
        int pos = atomicAdd(&lcur[p >> 16], 1);
        srcs[pos] = (int)(p & 0xffffu);
    }
}

// ---------------- GEMM: C[row][128] = dinv[row] * (A@W)[row], fp16 MFMA ----------------
__global__ __launch_bounds__(256) void gemm_mfma_f32in(const float* __restrict__ A,
                                                       const _Float16* __restrict__ wfrag,
                                                       const float* __restrict__ dinv,
                                                       _Float16* __restrict__ C, int M) {
    __shared__ _Float16 As[128 * 136];
    int t = threadIdx.x;
    int row0 = blockIdx.x * 128;

    const float4* A4 = (const float4*)A;
#pragma unroll
    for (int it = 0; it < 16; it++) {
        int v = it * 256 + t;
        int row = v >> 5;
        int seg = v & 31;
        float4 val = make_float4(0.f, 0.f, 0.f, 0.f);
        if (row0 + row < M) val = A4[(size_t)(row0 + row) * 32 + seg];
        _Float16* p = &As[row * 136 + seg * 4];
        p[0] = (_Float16)val.x; p[1] = (_Float16)val.y;
        p[2] = (_Float16)val.z; p[3] = (_Float16)val.w;
    }
    __syncthreads();

    int wv = t >> 6;
    int lane = t & 63;
    int lrow = lane & 15;
    int lq = lane >> 4;

    f32x4 acc[2][8];
#pragma unroll
    for (int i = 0; i < 2; i++)
#pragma unroll
        for (int j = 0; j < 8; j++) acc[i][j] = (f32x4){0.f, 0.f, 0.f, 0.f};

#pragma unroll
    for (int kc = 0; kc < 4; kc++) {
        int k0 = kc * 32;
        f16x8 a0 = *((const f16x8*)&As[(wv * 32 + lrow) * 136 + k0 + lq * 8]);
        f16x8 a1 = *((const f16x8*)&As[(wv * 32 + 16 + lrow) * 136 + k0 + lq * 8]);
#pragma unroll
        for (int nb = 0; nb < 8; nb++) {
            f16x8 b = ((const f16x8*)wfrag)[(nb * 4 + kc) * 64 + lane];
            acc[0][nb] = __builtin_amdgcn_mfma_f32_16x16x32_f16(a0, b, acc[0][nb], 0, 0, 0);
            acc[1][nb] = __builtin_amdgcn_mfma_f32_16x16x32_f16(a1, b, acc[1][nb], 0, 0, 0);
        }
    }

    // C/D layout: col = lane&15, row = (lane>>4)*4 + reg. Prescaled store.
#pragma unroll
    for (int ti = 0; ti < 2; ti++) {
#pragma unroll
        for (int r = 0; r < 4; r++) {
            int row = row0 + wv * 32 + ti * 16 + lq * 4 + r;
            if (row < M) {
                float sc = dinv[row];
#pragma unroll
                for (int nb = 0; nb < 8; nb++)
                    C[(size_t)row * 128 + nb * 16 + lrow] = (_Float16)(acc[ti][nb][r] * sc);
            }
        }
    }
}

// ---------------- agg: one wave per node, 4-edge-wide uint4 gather ----------------
// lane = slot(lane>>4) x feature-quad(lane&15). One uint4 load = 4 edges x
// 256B per instruction; unroll 4 -> 16 edges in flight. Table prescaled by
// dinv; self-loop added in slot 0; slot-reduce via 2 xor-shuffles.
// L1: ob[node] = dn * relu(dn*sum + b1)   (prescaled for next stage)
// L2: pool: block LDS reduce (4 consecutive nodes, ~same graph) + atomicAdd P.
template <bool L1>
__global__ __launch_bounds__(256) void agg(const _Float16* __restrict__ tab,
                                           const int* __restrict__ srcs,
                                           const int* __restrict__ row_start,
                                           const float* __restrict__ dinv,
                                           const float* __restrict__ bias,
                                           const int* __restrict__ batch,
                                           _Float16* __restrict__ obout,
                                           float* __restrict__ P, int n) {
    __shared__ float red[4][128];
    int wv = threadIdx.x >> 6;
    int lane = threadIdx.x & 63;
    int f = lane & 15;
    int slot = lane >> 4;
    int base = blockIdx.x * 4;
    int node = base + wv;
    const uint4* T4 = (const uint4*)tab;  // row = 16 uint4 (256B)
    float acc[8];
#pragma unroll
    for (int k = 0; k < 8; k++) acc[k] = 0.f;
    float dn = 0.f;
    if (node < n) {
        int s0 = row_start[node];
        int c = row_start[node + 1] - s0;
        dn = dinv[node];
        for (int e = 0; e < c; e += 16) {
            uint4 v[4];
            float m[4];
#pragma unroll
            for (int g = 0; g < 4; g++) {
                int idx = e + g * 4 + slot;
                int si = (idx < c) ? srcs[s0 + idx] : node;
                m[g] = (idx < c) ? 1.f : 0.f;
                v[g] = T4[(size_t)si * 16 + f];
            }
#pragma unroll
            for (int g = 0; g < 4; g++) {
                acc[0] = fmaf(m[g], f16lo(v[g].x), acc[0]);
                acc[1] = fmaf(m[g], f16hi(v[g].x), acc[1]);
                acc[2] = fmaf(m[g], f16lo(v[g].y), acc[2]);
                acc[3] = fmaf(m[g], f16hi(v[g].y), acc[3]);
                acc[4] = fmaf(m[g], f16lo(v[g].z), acc[4]);
                acc[5] = fmaf(m[g], f16hi(v[g].z), acc[5]);
                acc[6] = fmaf(m[g], f16lo(v[g].w), acc[6]);
                acc[7] = fmaf(m[g], f16hi(v[g].w), acc[7]);
            }
        }
        if (slot == 0) {  // self-loop, once
            uint4 hv = T4[(size_t)node * 16 + f];
            acc[0] += f16lo(hv.x); acc[1] += f16hi(hv.x);
            acc[2] += f16lo(hv.y); acc[3] += f16hi(hv.y);
            acc[4] += f16lo(hv.z); acc[5] += f16hi(hv.z);
            acc[6] += f16lo(hv.w); acc[7] += f16hi(hv.w);
        }
#pragma unroll
        for (int k = 0; k < 8; k++) {
            acc[k] += __shfl_xor(acc[k], 16);
            acc[k] += __shfl_xor(acc[k], 32);
        }
    }
    if (L1) {
        if (node < n && slot == 0) {
            float4 b0 = ((const float4*)bias)[f * 2];
            float4 b1 = ((const float4*)bias)[f * 2 + 1];
            float o0 = dn * fmaxf(fmaf(dn, acc[0], b0.x), 0.f);
            float o1 = dn * fmaxf(fmaf(dn, acc[1], b0.y), 0.f);
            float o2 = dn * fmaxf(fmaf(dn, acc[2], b0.z), 0.f);
            float o3 = dn * fmaxf(fmaf(dn, acc[3], b0.w), 0.f);
            float o4 = dn * fmaxf(fmaf(dn, acc[4], b1.x), 0.f);
            float o5 = dn * fmaxf(fmaf(dn, acc[5], b1.y), 0.f);
            float o6 = dn * fmaxf(fmaf(dn, acc[6], b1.z), 0.f);
            float o7 = dn * fmaxf(fmaf(dn, acc[7], b1.w), 0.f);
            uint4 w;
            w.x = pack2f16(o0, o1); w.y = pack2f16(o2, o3);
            w.z = pack2f16(o4, o5); w.w = pack2f16(o6, o7);
            ((uint4*)obout)[(size_t)node * 16 + f] = w;
        }
    } else {
        if (node < n && slot == 0) {
#pragma unroll
            for (int k = 0; k < 8; k++) red[wv][f * 8 + k] = dn * acc[k];
        }
        __syncthreads();
        int lastn = min(base + 3, n - 1);
        bool uniform = (base + 3 < n) && (batch[base] == batch[lastn]);
        if (uniform) {
            if (wv == 0 && slot == 0) {
                int g = batch[base];
#pragma unroll
                for (int k = 0; k < 8; k++) {
                    int ff = f * 8 + k;
                    float s = red[0][ff] + red[1][ff] + red[2][ff] + red[3][ff];
                    atomicAdd(&P[g * 128 + ff], s);
                }
            }
        } else if (node < n && slot == 0) {
            int g = batch[node];
#pragma unroll
            for (int k = 0; k < 8; k++)
                atomicAdd(&P[g * 128 + f * 8 + k], dn * acc[k]);
        }
    }
}

// ---------------- out = P @ W2 + n_g * b2, one block per graph ----------------
__global__ __launch_bounds__(128) void gemm_small(const float* __restrict__ P,
                                                  const float* __restrict__ W2,
                                                  const float* __restrict__ b2,
                                                  const int* __restrict__ batch,
                                                  float* __restrict__ out, int n) {
    __shared__ float prow[128];
    int g = blockIdx.x;
    int c = threadIdx.x;
    prow[c] = P[g * 128 + c];
    __syncthreads();
    int lo = 0, hi = n;
    while (lo < hi) { int mid = (lo + hi) >> 1; if (batch[mid] < g) lo = mid + 1; else hi = mid; }
    int start = lo;
    hi = n;
    while (lo < hi) { int mid = (lo + hi) >> 1; if (batch[mid] < g + 1) lo = mid + 1; else hi = mid; }
    float ng = (float)(lo - start);
    float acc = 0.f;
#pragma unroll 8
    for (int k = 0; k < 128; k++) acc = fmaf(prow[k], W2[k * 128 + c], acc);
    out[g * 128 + c] = acc + ng * b2[c];
}

extern "C" void kernel_launch(void* const* d_in, const int* in_sizes, int n_in,
                              void* d_out, int out_size, void* d_ws, size_t ws_size,
                              hipStream_t stream) {
    const float* x  = (const float*)d_in[0];
    const int*   ei = (const int*)d_in[1];
    const int*   batch = (const int*)d_in[2];
    const float* W1 = (const float*)d_in[3];
    const float* b1 = (const float*)d_in[4];
    const float* W2 = (const float*)d_in[5];
    const float* b2 = (const float*)d_in[6];
    float* out = (float*)d_out;

    const int N = in_sizes[2];       // 50000 (assumed <= 65536)
    const int E = in_sizes[1] / 2;   // 800000

    const int NB = (N + 255) >> 8;              // 196 buckets
    const int NBLK = (E + BCHUNK - 1) / BCHUNK; // 196 chunks
    const int ncounts = NB * NBLK;              // 38416

    // workspace layout
    _Float16* hb = (_Float16*)d_ws;                  // N*128 halves
    _Float16* ob = hb + (size_t)N * 128;             // N*128 halves
    int* row_start = (int*)(ob + (size_t)N * 128);   // N+1
    float* dinv    = (float*)(row_start + N + 1);    // N
    int* srcs      = (int*)(dinv + N);               // E
    unsigned int* bedges = (unsigned int*)(srcs + E);// E
    int* counts    = (int*)(bedges + E);             // NB*NBLK
    _Float16* wfrag1 = (_Float16*)(counts + ncounts);// 128*128
    float* P       = (float*)(wfrag1 + 128 * 128);   // 128*128 f32

    // 1. setup: wprep(W1) + zero P
    setup<<<(2048 + 128 * 128 + 255) / 256, 256, 0, stream>>>(W1, wfrag1, P);
    // 2-5. dst binning + CSR build
    bin_hist<<<NBLK, 256, 0, stream>>>(ei, counts, E, NB, NBLK);
    scan_counts<<<1, 1024, 0, stream>>>(counts, ncounts);
    bin_scatter<<<NBLK, 256, 0, stream>>>(ei, counts, bedges, E, NB, NBLK);
    fill_buckets<<<NB, 256, 0, stream>>>(bedges, counts, row_start, dinv, srcs, E, N, NB, NBLK);

    const int gemm_grid = (N + 127) / 128;
    const int agg_grid = (N + 3) / 4;

    // 6-7. layer 1: hb = dinv*(x@W1) ; ob = dinv*relu(dn*sum + b1)
    gemm_mfma_f32in<<<gemm_grid, 256, 0, stream>>>(x, wfrag1, dinv, hb, N);
    agg<true><<<agg_grid, 256, 0, stream>>>(hb, srcs, row_start, dinv, b1, nullptr,
                                            ob, nullptr, N);
    // 8-9. layer 2 (reordered): P = pool(Â o) ; out = P@W2 + n_g*b2
    agg<false><<<agg_grid, 256, 0, stream>>>(ob, srcs, row_start, dinv, nullptr, batch,
                                             nullptr, P, N);
    gemm_small<<<128, 128, 0, stream>>>(P, W2, b2, batch, out, N);
}